// Round 3
// baseline (487.475 us; speedup 1.0000x reference)
//
#include <hip/hip_runtime.h>

// SAGEConv mean-agg + concat-linear via device-built CSR:
//   deg -> scan (atomic block-base) -> fill -> gather-agg -> GEMM.
// R3: de-fused agg (low VGPR, 4-rows-per-load gather) + R1-style GEMM.

constexpr int FIN  = 64;
constexpr int FOUT = 64;

__global__ __launch_bounds__(256) void k_deg(const int* __restrict__ dst,
                                             int* __restrict__ deg, int n_edges) {
    int i = (blockIdx.x * 256 + threadIdx.x) * 4;
    if (i + 3 < n_edges) {
        int4 q = *(const int4*)(dst + i);
        atomicAdd(&deg[q.x], 1);
        atomicAdd(&deg[q.y], 1);
        atomicAdd(&deg[q.z], 1);
        atomicAdd(&deg[q.w], 1);
    } else {
        for (int k = i; k < n_edges; ++k) atomicAdd(&deg[dst[k]], 1);
    }
}

// exclusive scan, 1024 elems/block, block base allocated via atomicAdd(total).
// Node ranges are not in node order globally — only self-consistent, which is
// all the gather needs.
__global__ __launch_bounds__(256) void k_scan(const int* __restrict__ deg,
                                              int* __restrict__ row_start,
                                              int* __restrict__ total, int n) {
    __shared__ int sc[256];
    __shared__ int gbase;
    int t = threadIdx.x;
    int i0 = blockIdx.x * 1024 + t * 4;
    int v0 = 0, v1 = 0, v2 = 0, v3 = 0;
    if (i0 + 3 < n) {
        int4 q = *(const int4*)(deg + i0);
        v0 = q.x; v1 = q.y; v2 = q.z; v3 = q.w;
    } else {
        if (i0     < n) v0 = deg[i0];
        if (i0 + 1 < n) v1 = deg[i0 + 1];
        if (i0 + 2 < n) v2 = deg[i0 + 2];
        if (i0 + 3 < n) v3 = deg[i0 + 3];
    }
    int tsum = v0 + v1 + v2 + v3;
    sc[t] = tsum;
    __syncthreads();
    for (int off = 1; off < 256; off <<= 1) {
        int tmp = (t >= off) ? sc[t - off] : 0;
        __syncthreads();
        sc[t] += tmp;
        __syncthreads();
    }
    if (t == 255) gbase = atomicAdd(total, sc[255]);
    int excl = sc[t] - tsum;
    __syncthreads();
    int base = gbase + excl;
    if (i0     < n) row_start[i0]     = base;  base += v0;
    if (i0 + 1 < n) row_start[i0 + 1] = base;  base += v1;
    if (i0 + 2 < n) row_start[i0 + 2] = base;  base += v2;
    if (i0 + 3 < n) row_start[i0 + 3] = base;
}

__global__ __launch_bounds__(256) void k_fill(const int* __restrict__ src,
                                              const int* __restrict__ dst,
                                              const int* __restrict__ row_start,
                                              int* __restrict__ cursor,
                                              int* __restrict__ csr, int n_edges) {
    int i = (blockIdx.x * 256 + threadIdx.x) * 4;
    if (i + 3 < n_edges) {
        int4 s4 = *(const int4*)(src + i);
        int4 d4 = *(const int4*)(dst + i);
        int p0 = atomicAdd(&cursor[d4.x], 1);
        int p1 = atomicAdd(&cursor[d4.y], 1);
        int p2 = atomicAdd(&cursor[d4.z], 1);
        int p3 = atomicAdd(&cursor[d4.w], 1);
        csr[row_start[d4.x] + p0] = s4.x;
        csr[row_start[d4.y] + p1] = s4.y;
        csr[row_start[d4.z] + p2] = s4.z;
        csr[row_start[d4.w] + p3] = s4.w;
    } else {
        for (int k = i; k < n_edges; ++k) {
            int d = dst[k];
            int pos = atomicAdd(&cursor[d], 1);
            csr[row_start[d] + pos] = src[k];
        }
    }
}

// one wave per node. lane = (g = lane>>4 edge-slot, fl = lane&15 float4 chunk):
// each global_load_dwordx4 fetches 4 complete x-rows (4 edges consumed/inst).
__global__ __launch_bounds__(256) void k_agg(const float* __restrict__ x,
                                             const int* __restrict__ row_start,
                                             const int* __restrict__ deg,
                                             const int* __restrict__ csr,
                                             float* __restrict__ agg, int n_nodes) {
    int lane = threadIdx.x & 63;
    int n = blockIdx.x * 4 + (threadIdx.x >> 6);
    if (n >= n_nodes) return;
    int g  = lane >> 4;
    int fl = lane & 15;

    int start = row_start[n];   // wave-uniform
    int d     = deg[n];
    float4 acc = make_float4(0.f, 0.f, 0.f, 0.f);

    for (int base = 0; base < d; base += 64) {
        int cnt  = min(64, d - base);
        int sidx = csr[start + base + ((lane < cnt) ? lane : 0)];  // coalesced
        int nj = (cnt + 3) >> 2;
#pragma unroll 4
        for (int jj = 0; jj < nj; ++jj) {
            int ei = 4 * jj + g;            // this group's edge in the chunk
            int s  = __shfl(sidx, ei);
            if (ei < cnt) {
                float4 v = ((const float4*)(x + (size_t)s * FIN))[fl];
                acc.x += v.x; acc.y += v.y; acc.z += v.z; acc.w += v.w;
            }
        }
    }
    // reduce the 4 edge-slot groups (lanes L, L+16, L+32, L+48)
    acc.x += __shfl_xor(acc.x, 16); acc.y += __shfl_xor(acc.y, 16);
    acc.z += __shfl_xor(acc.z, 16); acc.w += __shfl_xor(acc.w, 16);
    acc.x += __shfl_xor(acc.x, 32); acc.y += __shfl_xor(acc.y, 32);
    acc.z += __shfl_xor(acc.z, 32); acc.w += __shfl_xor(acc.w, 32);

    if (lane < 16) {
        float dinv = 1.0f / fmaxf((float)d, 1.0f);
        float4 r = make_float4(acc.x * dinv, acc.y * dinv, acc.z * dinv, acc.w * dinv);
        ((float4*)(agg + (size_t)n * FIN))[fl] = r;
    }
}

// lane = node; W row index wave-uniform (waves 0-1 -> cols 0..31, 2-3 -> 32..63)
// so W/b go through the scalar cache.
__global__ __launch_bounds__(256) void k_out(const float* __restrict__ x,
                                             const float* __restrict__ agg,
                                             const int* __restrict__ deg,
                                             const float* __restrict__ W,
                                             const float* __restrict__ b,
                                             float* __restrict__ out, int n_nodes) {
    int local = threadIdx.x & 127;
    int half  = threadIdx.x >> 7;   // wave-uniform
    int n = blockIdx.x * 128 + local;
    if (n >= n_nodes) return;

    const float* rowa = agg + (size_t)n * FIN;
    const float* rowx = x   + (size_t)n * FIN;

    float acc[32];
#pragma unroll
    for (int j = 0; j < 32; ++j) acc[j] = b[half * 32 + j];

    for (int c = 0; c < 4; ++c) {
        const float* rsrc = (c < 2) ? (rowa + c * 32) : (rowx + (c - 2) * 32);
        float hr[32];
#pragma unroll
        for (int i = 0; i < 8; ++i) {
            float4 v = ((const float4*)rsrc)[i];
            hr[4*i] = v.x; hr[4*i+1] = v.y; hr[4*i+2] = v.z; hr[4*i+3] = v.w;
        }
        const float* wbase = W + c * 32;
#pragma unroll
        for (int j = 0; j < 32; ++j) {
            const float* wr = wbase + (size_t)(half * 32 + j) * 128;
#pragma unroll
            for (int kk = 0; kk < 32; ++kk)
                acc[j] = fmaf(hr[kk], wr[kk], acc[j]);
        }
    }

    float4* o = (float4*)(out + (size_t)n * FOUT + half * 32);
#pragma unroll
    for (int j = 0; j < 8; ++j)
        o[j] = make_float4(acc[4*j], acc[4*j+1], acc[4*j+2], acc[4*j+3]);
}

extern "C" void kernel_launch(void* const* d_in, const int* in_sizes, int n_in,
                              void* d_out, int out_size, void* d_ws, size_t ws_size,
                              hipStream_t stream) {
    const float* x  = (const float*)d_in[0];
    const int*   ei = (const int*)d_in[1];
    const float* W  = (const float*)d_in[3];
    const float* b  = (const float*)d_in[4];
    float* out = (float*)d_out;

    int n_nodes = in_sizes[0] / FIN;
    int n_edges = in_sizes[1] / 2;
    const int* src = ei;
    const int* dst = ei + n_edges;

    // ws (ints): deg[N] | cursor[N] | total[1]+pad3 | row_start[N] | csr[E] | agg fp32[N*64]
    int* wsi       = (int*)d_ws;
    int* deg       = wsi;
    int* cursor    = wsi + n_nodes;
    int* total     = wsi + 2 * n_nodes;
    int* row_start = wsi + 2 * n_nodes + 4;
    int* csr       = wsi + 3 * n_nodes + 4;
    float* agg     = (float*)(wsi + 3 * n_nodes + 4 + n_edges);

    hipMemsetAsync(d_ws, 0, (size_t)(2 * n_nodes + 4) * sizeof(int), stream);

    // note: mean-divide uses max(deg,1); deg==0 rows get zeros in k_agg (no
    // dependence on the 0xAA-poisoned agg region — it's fully overwritten).
    int e4b = (n_edges / 4 + 255) / 256 + 1;
    k_deg<<<e4b, 256, 0, stream>>>(dst, deg, n_edges);
    k_scan<<<(n_nodes + 1023) / 1024, 256, 0, stream>>>(deg, row_start, total, n_nodes);
    k_fill<<<e4b, 256, 0, stream>>>(src, dst, row_start, cursor, csr, n_edges);
    k_agg<<<(n_nodes + 3) / 4, 256, 0, stream>>>(x, row_start, deg, csr, agg, n_nodes);
    k_out<<<(n_nodes + 127) / 128, 256, 0, stream>>>(x, agg, deg, W, b, out, n_nodes);
}